// Round 10
// baseline (35.603 us; speedup 1.0000x reference)
//
#include <hip/hip_runtime.h>

#define BB 2
#define CC 64
#define CI 32
#define NPIX 9216          // 96*96
#define CH 128             // pixels per chunk/block
#define NCHK (NPIX / CH)   // 72 chunks per batch
#define NB (BB * NCHK)     // 144 blocks
#define SLOT_U64 (CI * CI / 2)  // 512 u64 per M-partial slot

static __device__ __forceinline__ unsigned long long pack2(float a, float b) {
  return ((unsigned long long)__float_as_uint(b) << 32) |
         (unsigned long long)__float_as_uint(a);
}

struct Phase2 {
  float Ms[CI][CI + 1];   // 4.2 KB
  float T1[CI][CC + 2];   // 8.4 KB
  float Wt[CC][CC + 2];   // 16.9 KB   Wt[in_j][out_o]
  float t2[CI];
  float bl[CC];
};
struct Phase1 {
  float pgw[2 * CI][CC + 1];  // 16.6 KB (pw rows 0..31, gw rows 32..63)
  float Ps[CI][CH + 4];       // 16.9 KB
  float Gs[CI][CH + 4];       // 16.9 KB
};
struct Smem {
  float xt[CC][CH + 4];       // 33.8 KB — persists phase1 -> apply
  union { Phase1 p1; Phase2 p2; float2 red[2 * SLOT_U64]; } u;  // 50.4 KB
};

__global__ __launch_bounds__(512) void fused_nonlocal(
    const float* __restrict__ x, const float* __restrict__ tw,
    const float* __restrict__ tb, const float* __restrict__ pw,
    const float* __restrict__ pb, const float* __restrict__ gw,
    const float* __restrict__ gb, const float* __restrict__ rw,
    const float* __restrict__ rb, float* __restrict__ z,
    unsigned long long* __restrict__ Mpart, unsigned int* __restrict__ ctr) {
  __shared__ __align__(16) Smem sm;
  const int t = threadIdx.x;
  const int blk = blockIdx.x;
  const int batch = blk / NCHK;
  const int chk = blk - batch * NCHK;
  const float* __restrict__ X = x + (size_t)batch * CC * NPIX + chk * CH;

  // ---------------- phase 1: stage X + weights, P'/G', M_c -> slot ----------
  // stage X chunk (64ch x 128px): 2048 float4, 4/thread, coalesced
#pragma unroll
  for (int h = 0; h < 4; ++h) {
    const int idx = t + 512 * h;
    const int c = idx >> 5;
    const int p4 = (idx & 31) * 4;
    *reinterpret_cast<float4*>(&sm.xt[c][p4]) =
        *reinterpret_cast<const float4*>(&X[(size_t)c * NPIX + p4]);
  }
#pragma unroll
  for (int h = 0; h < 4; ++h) {
    const int idx = t + 512 * h;
    const int k = idx >> 6, c = idx & 63;
    sm.u.p1.pgw[k][c] = pw[idx];
    sm.u.p1.pgw[CI + k][c] = gw[idx];
  }
  __syncthreads();

  // P' = pw X + pb, G' = gw X + gb : thread = (k = t&31, 8-px strip)
  {
    const int k = t & 31;
    const int p0 = (t >> 5) * 8;
    float pa[8] = {};
    float ga[8] = {};
    for (int c = 0; c < CC; ++c) {
      const float4 x0 = *reinterpret_cast<const float4*>(&sm.xt[c][p0]);
      const float4 x1 = *reinterpret_cast<const float4*>(&sm.xt[c][p0 + 4]);
      const float pv = sm.u.p1.pgw[k][c];
      const float gv = sm.u.p1.pgw[CI + k][c];
      const float xa[8] = {x0.x, x0.y, x0.z, x0.w, x1.x, x1.y, x1.z, x1.w};
#pragma unroll
      for (int i = 0; i < 8; ++i) {
        pa[i] += pv * xa[i];
        ga[i] += gv * xa[i];
      }
    }
    const float pbk = pb[k];
    const float gbk = gb[k];
    float4 o0 = make_float4(pa[0] + pbk, pa[1] + pbk, pa[2] + pbk, pa[3] + pbk);
    float4 o1 = make_float4(pa[4] + pbk, pa[5] + pbk, pa[6] + pbk, pa[7] + pbk);
    *reinterpret_cast<float4*>(&sm.u.p1.Ps[k][p0]) = o0;
    *reinterpret_cast<float4*>(&sm.u.p1.Ps[k][p0 + 4]) = o1;
    o0 = make_float4(ga[0] + gbk, ga[1] + gbk, ga[2] + gbk, ga[3] + gbk);
    o1 = make_float4(ga[4] + gbk, ga[5] + gbk, ga[6] + gbk, ga[7] + gbk);
    *reinterpret_cast<float4*>(&sm.u.p1.Gs[k][p0]) = o0;
    *reinterpret_cast<float4*>(&sm.u.p1.Gs[k][p0 + 4]) = o1;
  }
  __syncthreads();

  // M_c = P' G'^T : thread -> u64 slot element kk*16+l = {M[kk][l], M[kk][l+16]}
  // Agent-scope relaxed atomic store (sc1 write-through: no dirty L2 lines).
  {
    const int kk = t >> 4;
    const int l = t & 15;
    float ma = 0.f, mb = 0.f;
    for (int p4 = 0; p4 < CH; p4 += 4) {
      const float4 pv = *reinterpret_cast<const float4*>(&sm.u.p1.Ps[kk][p4]);
      const float4 g0 = *reinterpret_cast<const float4*>(&sm.u.p1.Gs[l][p4]);
      const float4 g1 =
          *reinterpret_cast<const float4*>(&sm.u.p1.Gs[l + 16][p4]);
      ma += pv.x * g0.x + pv.y * g0.y + pv.z * g0.z + pv.w * g0.w;
      mb += pv.x * g1.x + pv.y * g1.y + pv.z * g1.z + pv.w * g1.w;
    }
    unsigned long long* Mp = Mpart + (size_t)blk * SLOT_U64;
    __hip_atomic_store(&Mp[kk * 16 + l], pack2(ma, mb), __ATOMIC_RELAXED,
                       __HIP_MEMORY_SCOPE_AGENT);
  }

  // ---------------- barrier: syncthreads drains vmcnt -> stores acked -------
  __syncthreads();
  if (t == 0) {
    __hip_atomic_fetch_add(ctr, 1u, __ATOMIC_RELAXED,
                           __HIP_MEMORY_SCOPE_AGENT);
    while (__hip_atomic_load(ctr, __ATOMIC_RELAXED,
                             __HIP_MEMORY_SCOPE_AGENT) < (unsigned)NB) {
      __builtin_amdgcn_s_sleep(2);
    }
  }
  __syncthreads();

  // ---------------- phase 2: M-reduce (sc1 loads), algebra, apply ----------
  {
    // reduce 72 slots, half-split: thread = (e = t&255, half = t>>8)
    const int e = t & 255;
    const int half = t >> 8;
    const unsigned long long* __restrict__ Mp =
        Mpart + (size_t)batch * NCHK * SLOT_U64;
    float sa0 = 0.f, sb0 = 0.f, sa1 = 0.f, sb1 = 0.f;
#pragma unroll 4
    for (int k = half * 36; k < half * 36 + 36; ++k) {
      const unsigned long long v0 = __hip_atomic_load(
          &Mp[(size_t)k * SLOT_U64 + e], __ATOMIC_RELAXED,
          __HIP_MEMORY_SCOPE_AGENT);
      const unsigned long long v1 = __hip_atomic_load(
          &Mp[(size_t)k * SLOT_U64 + 256 + e], __ATOMIC_RELAXED,
          __HIP_MEMORY_SCOPE_AGENT);
      sa0 += __uint_as_float((unsigned)v0);
      sb0 += __uint_as_float((unsigned)(v0 >> 32));
      sa1 += __uint_as_float((unsigned)v1);
      sb1 += __uint_as_float((unsigned)(v1 >> 32));
    }
    sm.u.red[half * 512 + e] = make_float2(sa0, sb0);
    sm.u.red[half * 512 + 256 + e] = make_float2(sa1, sb1);
  }
  __syncthreads();
  {
    // combine halves -> Ms.  u64 elem q: kk=q>>4, l=q&15 -> M[kk][l], M[kk][l+16]
    const float2 a = sm.u.red[t];
    const float2 b = sm.u.red[512 + t];
    const int kk = t >> 4;
    const int l = t & 15;
    // NOTE: red[] aliases Ms in the union -- must read before write; barrier:
    const float msa = a.x + b.x;
    const float msb = a.y + b.y;
    __syncthreads();
    sm.u.p2.Ms[kk][l] = msa;
    sm.u.p2.Ms[kk][l + 16] = msb;
  }
  __syncthreads();

  // T1[c][j] = sum_k Ms[k][c] tw[k][j];  t2[c] = sum_k Ms[k][c] tb[k]
  {
    const int j = t & 63;
    const int c0 = (t >> 6) * 4;
#pragma unroll
    for (int cc = 0; cc < 4; ++cc) {
      const int c = c0 + cc;
      float s = 0.f;
      for (int k = 0; k < CI; ++k) s += sm.u.p2.Ms[k][c] * tw[k * CC + j];
      sm.u.p2.T1[c][j] = s;
    }
    if (t < CI) {
      float s = 0.f;
      for (int k = 0; k < CI; ++k) s += sm.u.p2.Ms[k][t] * tb[k];
      sm.u.p2.t2[t] = s;
    }
  }
  __syncthreads();

  // Wt[j][o] = invN * sum_c rw[o][c] T1[c][j];  bl = invN*rw.t2 + rb
  {
    const float invN = 1.0f / (float)NPIX;
    const int j = t & 63;
    const int o0 = (t >> 6) * 8;
#pragma unroll
    for (int oo = 0; oo < 8; ++oo) {
      const int o = o0 + oo;
      float s = 0.f;
      for (int c = 0; c < CI; ++c) s += rw[o * CI + c] * sm.u.p2.T1[c][j];
      sm.u.p2.Wt[j][o] = s * invN;
    }
    if (t < CC) {
      float s = 0.f;
      for (int c = 0; c < CI; ++c) s += rw[t * CI + c] * sm.u.p2.t2[c];
      sm.u.p2.bl[t] = s * invN + rb[t];
    }
  }
  __syncthreads();

  // apply: Z = X + W X + b   (thread = 8 out-ch x 2 px; xt still in LDS)
  {
    const int n0 = chk * CH;
    float* __restrict__ Z = z + (size_t)batch * CC * NPIX;
    const int c0 = (t >> 6) * 8;
    const int m0 = (t & 63) * 2;
    float acc[8][2] = {};
#pragma unroll 8
    for (int k = 0; k < CC; ++k) {
      const float2 xv = *reinterpret_cast<const float2*>(&sm.xt[k][m0]);
      const float4 w0 = *reinterpret_cast<const float4*>(&sm.u.p2.Wt[k][c0]);
      const float4 w1 =
          *reinterpret_cast<const float4*>(&sm.u.p2.Wt[k][c0 + 4]);
      const float wa[8] = {w0.x, w0.y, w0.z, w0.w, w1.x, w1.y, w1.z, w1.w};
#pragma unroll
      for (int cc = 0; cc < 8; ++cc) {
        acc[cc][0] += wa[cc] * xv.x;
        acc[cc][1] += wa[cc] * xv.y;
      }
    }
#pragma unroll
    for (int cc = 0; cc < 8; ++cc) {
      const int c = c0 + cc;
      const float2 xr = *reinterpret_cast<const float2*>(&sm.xt[c][m0]);
      const float bb2 = sm.u.p2.bl[c];
      float2 o;
      o.x = acc[cc][0] + xr.x + bb2;
      o.y = acc[cc][1] + xr.y + bb2;
      *reinterpret_cast<float2*>(&Z[(size_t)c * NPIX + n0 + m0]) = o;
    }
  }
}

extern "C" void kernel_launch(void* const* d_in, const int* in_sizes, int n_in,
                              void* d_out, int out_size, void* d_ws,
                              size_t ws_size, hipStream_t stream) {
  (void)in_sizes; (void)n_in; (void)out_size; (void)ws_size;
  const float* x  = (const float*)d_in[0];
  const float* tw = (const float*)d_in[1];
  const float* tb = (const float*)d_in[2];
  const float* pw = (const float*)d_in[3];
  const float* pb = (const float*)d_in[4];
  const float* gw = (const float*)d_in[5];
  const float* gb = (const float*)d_in[6];
  const float* rw = (const float*)d_in[7];
  const float* rb = (const float*)d_in[8];
  float* z = (float*)d_out;

  unsigned long long* Mpart = (unsigned long long*)d_ws;  // NB*512 u64
  unsigned int* ctr = (unsigned int*)(Mpart + (size_t)NB * SLOT_U64);

  hipMemsetAsync(ctr, 0, sizeof(unsigned int), stream);
  hipLaunchKernelGGL(fused_nonlocal, dim3(NB), dim3(512), 0, stream,
                     x, tw, tb, pw, pb, gw, gb, rw, rb, z, Mpart, ctr);
}

// Round 11
// 32.075 us; speedup vs baseline: 1.1100x; 1.1100x over previous
//
#include <hip/hip_runtime.h>

#define BB 2
#define CC 64
#define CI 32
#define NPIX 9216          // 96*96
#define CH 128             // pixels per chunk/block
#define NCHK (NPIX / CH)   // 72 chunks per batch
#define NB (BB * NCHK)     // 144 blocks
#define SLOT (CI * CI)     // 1024 floats per M-partial slot

// ---------------------------------------------------------------------------
// k1: per-(batch,chunk) partial M_c = (pw Xc + pb 1^T)(gw Xc + gb 1^T)^T
//     -> distinct slot (plain stores). 1024 threads = 4 waves/SIMD.
// ---------------------------------------------------------------------------
__global__ __launch_bounds__(1024) void k1_Mpart(
    const float* __restrict__ x, const float* __restrict__ pw,
    const float* __restrict__ pb, const float* __restrict__ gw,
    const float* __restrict__ gb, float* __restrict__ Mpart) {
  __shared__ float xt[CC][CH + 4];      // 33.8 KB
  __shared__ float pgw[2 * CI][CC + 1]; // 16.6 KB
  __shared__ float Ps[CI][CH + 4];      // 16.9 KB
  __shared__ float Gs[CI][CH + 4];      // 16.9 KB
  const int t = threadIdx.x;
  const int blk = blockIdx.x;
  const int batch = blk / NCHK;
  const int chk = blk - batch * NCHK;
  const float* __restrict__ X = x + (size_t)batch * CC * NPIX + chk * CH;

  // stage X chunk (64ch x 128px): 2048 float4, 2/thread, coalesced
#pragma unroll
  for (int h = 0; h < 2; ++h) {
    const int idx = t + 1024 * h;
    const int c = idx >> 5;
    const int p4 = (idx & 31) * 4;
    *reinterpret_cast<float4*>(&xt[c][p4]) =
        *reinterpret_cast<const float4*>(&X[(size_t)c * NPIX + p4]);
  }
  // stage pw+gw (32x64 each)
#pragma unroll
  for (int h = 0; h < 2; ++h) {
    const int idx = t + 1024 * h;
    const int k = idx >> 6, c = idx & 63;
    pgw[k][c] = pw[idx];
    pgw[CI + k][c] = gw[idx];
  }
  __syncthreads();

  // P' = pw X + pb, G' = gw X + gb : thread = (k = t&31, 4-px strip)
  {
    const int k = t & 31;
    const int p0 = (t >> 5) * 4;
    float pa[4] = {};
    float ga[4] = {};
    for (int c = 0; c < CC; ++c) {
      const float4 xv = *reinterpret_cast<const float4*>(&xt[c][p0]);
      const float pv = pgw[k][c];
      const float gv = pgw[CI + k][c];
      pa[0] += pv * xv.x; pa[1] += pv * xv.y;
      pa[2] += pv * xv.z; pa[3] += pv * xv.w;
      ga[0] += gv * xv.x; ga[1] += gv * xv.y;
      ga[2] += gv * xv.z; ga[3] += gv * xv.w;
    }
    const float pbk = pb[k];
    const float gbk = gb[k];
    *reinterpret_cast<float4*>(&Ps[k][p0]) =
        make_float4(pa[0] + pbk, pa[1] + pbk, pa[2] + pbk, pa[3] + pbk);
    *reinterpret_cast<float4*>(&Gs[k][p0]) =
        make_float4(ga[0] + gbk, ga[1] + gbk, ga[2] + gbk, ga[3] + gbk);
  }
  __syncthreads();

  // M_c[kk][l] = dot(Ps[kk], Gs[l]) over 128 px : one output per thread
  {
    const int kk = t >> 5;
    const int l = t & 31;
    float m = 0.f;
    for (int p4 = 0; p4 < CH; p4 += 4) {
      const float4 pv = *reinterpret_cast<const float4*>(&Ps[kk][p4]);
      const float4 gv = *reinterpret_cast<const float4*>(&Gs[l][p4]);
      m += pv.x * gv.x + pv.y * gv.y + pv.z * gv.z + pv.w * gv.w;
    }
    Mpart[(size_t)blk * SLOT + t] = m;  // element index == t (kk*32+l)
  }
}

// ---------------------------------------------------------------------------
// k2: per-block: reduce 72 M-partials -> M, algebra
//     (W = rw M^T tw / N, b = rw M^T tb / N + rb), apply Z = X + W X + b.
//     1024 threads = 4 waves/SIMD.
// ---------------------------------------------------------------------------
__global__ __launch_bounds__(1024) void k2_apply(
    const float* __restrict__ x, const float* __restrict__ tw,
    const float* __restrict__ tb, const float* __restrict__ rw,
    const float* __restrict__ rb, const float* __restrict__ Mpart,
    float* __restrict__ z) {
  __shared__ float xt[CC][CH + 4];   // 33.8 KB
  __shared__ float Ms[CI][CI + 1];   // 4.2 KB
  __shared__ float T1[CI][CC + 2];   // 8.4 KB
  __shared__ float Wt[CC][CC + 2];   // 16.9 KB   Wt[in_j][out_o]
  __shared__ float t2[CI];
  __shared__ float bl[CC];
  const int t = threadIdx.x;
  const int blk = blockIdx.x;
  const int batch = blk / NCHK;
  const int chk = blk - batch * NCHK;

  // stage x tile (2048 float4, 2/thread)
#pragma unroll
  for (int h = 0; h < 2; ++h) {
    const int idx = t + 1024 * h;
    const int c = idx >> 5;
    const int p4 = (idx & 31) * 4;
    *reinterpret_cast<float4*>(&xt[c][p4]) = *reinterpret_cast<const float4*>(
        &x[(size_t)batch * CC * NPIX + (size_t)c * NPIX + chk * CH + p4]);
  }

  // M-reduce: thread t owns element t; 72 coalesced loads, fixed order
  {
    const float* __restrict__ Mp = Mpart + (size_t)batch * NCHK * SLOT + t;
    float s = 0.f;
#pragma unroll 8
    for (int k = 0; k < NCHK; ++k) s += Mp[(size_t)k * SLOT];
    Ms[t >> 5][t & 31] = s;
  }
  __syncthreads();

  // T1[c][j] = sum_k Ms[k][c] tw[k][j];  t2[c] = sum_k Ms[k][c] tb[k]
  {
#pragma unroll
    for (int q = 0; q < 2; ++q) {
      const int idx = t + 1024 * q;
      const int c = idx >> 6, j = idx & 63;
      float s = 0.f;
      for (int k = 0; k < CI; ++k) s += Ms[k][c] * tw[k * CC + j];
      T1[c][j] = s;
    }
    if (t < CI) {
      float s = 0.f;
      for (int k = 0; k < CI; ++k) s += Ms[k][t] * tb[k];
      t2[t] = s;
    }
  }
  __syncthreads();

  // Wt[j][o] = invN * sum_c rw[o][c] T1[c][j];  bl = invN*rw.t2 + rb
  {
    const float invN = 1.0f / (float)NPIX;
#pragma unroll
    for (int q = 0; q < 4; ++q) {
      const int idx = t + 1024 * q;
      const int o = idx >> 6, j = idx & 63;
      float s = 0.f;
      for (int c = 0; c < CI; ++c) s += rw[o * CI + c] * T1[c][j];
      Wt[j][o] = s * invN;
    }
    if (t < CC) {
      float s = 0.f;
      for (int c = 0; c < CI; ++c) s += rw[t * CI + c] * t2[c];
      bl[t] = s * invN + rb[t];
    }
  }
  __syncthreads();

  // apply: Z = X + W X + b : thread = (8 out-ch, 1 px)
  {
    const int n0 = chk * CH;
    float* __restrict__ Z = z + (size_t)batch * CC * NPIX;
    const int c0 = (t >> 7) * 8;
    const int m0 = t & 127;
    float acc[8] = {};
#pragma unroll 8
    for (int k = 0; k < CC; ++k) {
      const float xv = xt[k][m0];
      const float4 w0 = *reinterpret_cast<const float4*>(&Wt[k][c0]);
      const float4 w1 = *reinterpret_cast<const float4*>(&Wt[k][c0 + 4]);
      acc[0] += w0.x * xv; acc[1] += w0.y * xv;
      acc[2] += w0.z * xv; acc[3] += w0.w * xv;
      acc[4] += w1.x * xv; acc[5] += w1.y * xv;
      acc[6] += w1.z * xv; acc[7] += w1.w * xv;
    }
#pragma unroll
    for (int cc = 0; cc < 8; ++cc) {
      const int c = c0 + cc;
      Z[(size_t)c * NPIX + n0 + m0] = acc[cc] + xt[c][m0] + bl[c];
    }
  }
}

extern "C" void kernel_launch(void* const* d_in, const int* in_sizes, int n_in,
                              void* d_out, int out_size, void* d_ws,
                              size_t ws_size, hipStream_t stream) {
  (void)in_sizes; (void)n_in; (void)out_size; (void)ws_size;
  const float* x  = (const float*)d_in[0];
  const float* tw = (const float*)d_in[1];
  const float* tb = (const float*)d_in[2];
  const float* pw = (const float*)d_in[3];
  const float* pb = (const float*)d_in[4];
  const float* gw = (const float*)d_in[5];
  const float* gb = (const float*)d_in[6];
  const float* rw = (const float*)d_in[7];
  const float* rb = (const float*)d_in[8];
  float* z = (float*)d_out;

  float* Mpart = (float*)d_ws;  // NB * 1024 floats = 589 KB

  hipLaunchKernelGGL(k1_Mpart, dim3(NB), dim3(1024), 0, stream,
                     x, pw, pb, gw, gb, Mpart);
  hipLaunchKernelGGL(k2_apply, dim3(NB), dim3(1024), 0, stream,
                     x, tw, tb, rw, rb, Mpart, z);
}